// Round 2
// baseline (3686.292 us; speedup 1.0000x reference)
//
#include <hip/hip_runtime.h>

#define NN     100000
#define NP     100096   // padded to multiple of 128
#define HD     128
#define NE     400000
#define TOT    2400000  // 6 * NE
#define L6     600000   // NN * 6 (per node,type counts)
#define NLAYER 8
#define SCHUNK 2048

typedef unsigned short ushort_t;
typedef unsigned int   uint_t;

typedef __bf16 bf16x8 __attribute__((ext_vector_type(8)));
typedef float  f32x4  __attribute__((ext_vector_type(4)));

__device__ __forceinline__ f32x4 mfma16(bf16x8 a, bf16x8 b, f32x4 c) {
  return __builtin_amdgcn_mfma_f32_16x16x32_bf16(a, b, c, 0, 0, 0);
}

__device__ __forceinline__ unsigned short f2bf(float f) {
  unsigned int u = __builtin_bit_cast(unsigned int, f);
  u = (u + 0x7FFFu + ((u >> 16) & 1u)) >> 16;
  return (unsigned short)u;
}
__device__ __forceinline__ float bflo(uint_t v) { return __builtin_bit_cast(float, v << 16); }
__device__ __forceinline__ float bfhi(uint_t v) { return __builtin_bit_cast(float, v & 0xFFFF0000u); }
__device__ __forceinline__ uint_t packbf(float x, float y) {
  return (uint_t)f2bf(x) | ((uint_t)f2bf(y) << 16);
}

#define GLOAD_LDS16(g, l) __builtin_amdgcn_global_load_lds( \
    (__attribute__((address_space(1))) void*)(g),           \
    (__attribute__((address_space(3))) void*)(l), 16, 0, 0)

// ---------- setup kernels (once per call) ----------

__global__ __launch_bounds__(256) void k_init(const float* __restrict__ ns,
    float* __restrict__ oh, float* __restrict__ oold, ushort_t* __restrict__ hbf) {
  int i = blockIdx.x * 256 + threadIdx.x;
  if (i < NN * HD) {
    float v = ns[i];
    oh[i] = v; oold[i] = v; hbf[i] = f2bf(v);
  }
}

__global__ __launch_bounds__(256) void k_prep(const float* __restrict__ Wm,
    const float* __restrict__ wih, const float* __restrict__ whh,
    ushort_t* __restrict__ Wcat, ushort_t* __restrict__ wihb, ushort_t* __restrict__ whhb) {
  int t = blockIdx.x * 256 + threadIdx.x;
  if (t < 128 * 768) {
    int n = t / 768, k = t % 768;
    int e = k >> 7, d = k & 127;
    // Wcat[n][k] = W_msg[e][d][n]  (B stored N-major so frags are K-contiguous)
    Wcat[t] = f2bf(Wm[(e * 128 + d) * 128 + n]);
  }
  if (t < 384 * 128) {
    wihb[t] = f2bf(wih[t]);
    whhb[t] = f2bf(whh[t]);
  }
}

__global__ __launch_bounds__(256) void k_hist(const int* __restrict__ edges, int* __restrict__ cnt6) {
  int t = blockIdx.x * 256 + threadIdx.x;
  if (t >= TOT) return;
  int e = t / NE, m = t - e * NE;
  int tgt;
  if (e < 3) tgt = edges[(e * NE + m) * 2 + 1];
  else       tgt = edges[((e - 3) * NE + m) * 2];
  atomicAdd(&cnt6[tgt * 6 + e], 1);
}

__global__ __launch_bounds__(256) void k_div(const int* __restrict__ cnt6,
    float* __restrict__ divf) {
  int i = blockIdx.x * 256 + threadIdx.x;
  if (i < NN) {
    int c = 0;
#pragma unroll
    for (int e = 0; e < 6; e++) c += cnt6[i * 6 + e];
    divf[i] = c ? (float)c : 1.0f;
  }
}

// exclusive scan over cnt6 (length L6) -> offs6 (length L6+1)
__global__ __launch_bounds__(256) void k_scan1(const int* __restrict__ cnt, int* __restrict__ bsum) {
  int base = blockIdx.x * SCHUNK + threadIdx.x * 8;
  int s = 0;
#pragma unroll
  for (int j = 0; j < 8; j++) { int idx = base + j; s += (idx < L6) ? cnt[idx] : 0; }
  for (int o = 32; o > 0; o >>= 1) s += __shfl_down(s, o);
  __shared__ int sm[4];
  if ((threadIdx.x & 63) == 0) sm[threadIdx.x >> 6] = s;
  __syncthreads();
  if (threadIdx.x == 0) bsum[blockIdx.x] = sm[0] + sm[1] + sm[2] + sm[3];
}

__global__ __launch_bounds__(512) void k_scan2(int* __restrict__ bsum, int nb) { // 1 block, nb<=512
  int t = threadIdx.x, lane = t & 63, wv = t >> 6;
  int orig = (t < nb) ? bsum[t] : 0;
  int v = orig;
  for (int o = 1; o < 64; o <<= 1) { int x = __shfl_up(v, o); if (lane >= o) v += x; }
  __shared__ int ws[8];
  if (lane == 63) ws[wv] = v;
  __syncthreads();
  int add = 0;
  for (int w = 0; w < wv; w++) add += ws[w];
  if (t < nb) bsum[t] = v - orig + add;   // exclusive
}

__global__ __launch_bounds__(256) void k_scan3(const int* __restrict__ cnt,
    const int* __restrict__ bsum, int* __restrict__ offs) {
  int base = blockIdx.x * SCHUNK + threadIdx.x * 8;
  int vals[8], pre[8];
  int s = 0;
#pragma unroll
  for (int j = 0; j < 8; j++) {
    int idx = base + j;
    vals[j] = (idx < L6) ? cnt[idx] : 0;
    pre[j] = s; s += vals[j];
  }
  int lane = threadIdx.x & 63, wvi = threadIdx.x >> 6;
  int v = s;
  for (int o = 1; o < 64; o <<= 1) { int t = __shfl_up(v, o); if (lane >= o) v += t; }
  __shared__ int wsum[4];
  if (lane == 63) wsum[wvi] = v;
  __syncthreads();
  int wpre = 0;
  for (int w = 0; w < wvi; w++) wpre += wsum[w];
  int texcl = (v - s) + wpre + bsum[blockIdx.x];
#pragma unroll
  for (int j = 0; j < 8; j++) {
    int idx = base + j;
    if (idx < L6) {
      offs[idx] = texcl + pre[j];
      if (idx == L6 - 1) offs[L6] = texcl + pre[j] + vals[j];
    }
  }
}

__global__ __launch_bounds__(256) void k_fill(const int* __restrict__ edges,
    int* __restrict__ cursor6, int* __restrict__ entries) {
  int t = blockIdx.x * 256 + threadIdx.x;
  if (t >= TOT) return;
  int e = t / NE, m = t - e * NE;
  int src, tgt;
  if (e < 3) { int b = (e * NE + m) * 2;       src = edges[b];     tgt = edges[b + 1]; }
  else       { int b = ((e - 3) * NE + m) * 2; src = edges[b + 1]; tgt = edges[b]; }
  int pos = atomicAdd(&cursor6[tgt * 6 + e], 1);
  entries[pos] = src;   // type implied by segment
}

// ---------- per-layer kernels ----------

// Fused aggregate+GEMM: block = 128 nodes, 8 waves (2x2 wave grid reused per
// wr=wv>>1 (0..3)? -> waves arranged 4 rows x 2 cols; each wave owns 32x64 of
// the 128x128 output. Per edge type e: aggregate neighbor sums into swizzled
// LDS A-tile, stage W_e into swizzled LDS B-tile, MFMA K=128, accumulate.
__global__ __launch_bounds__(512) void k_msg(const ushort_t* __restrict__ hbf,
    const int* __restrict__ offs6, const int* __restrict__ entries,
    const ushort_t* __restrict__ Wcat, const int* __restrict__ cnt6,
    const float* __restrict__ divf, const float* __restrict__ b_msg,
    ushort_t* __restrict__ msgs) {
  __shared__ ushort_t Alds[128 * 128];   // 32KB, XOR-swizzled rows (256B stride)
  __shared__ ushort_t Blds[128 * 128];   // 32KB, XOR-swizzled via source permute
  int lane = threadIdx.x & 63, wv = threadIdx.x >> 6;
  int wr = wv >> 1, wc = wv & 1;         // 4x2 wave grid: 32 rows x 64 cols each
  int rbase = blockIdx.x * 128;
  f32x4 acc[2][4] = {};
  for (int e = 0; e < 6; e++) {
    // stage W_e: linear LDS dest, inverse-swizzled global source (rule #21)
#pragma unroll
    for (int i = 0; i < 4; i++) {
      int off = i * 8192 + wv * 1024;        // wave-uniform LDS byte base
      int q = off + lane * 16;               // this lane's implicit dest slot
      int row = q >> 8;
      int colb = (q & 255) ^ ((row & 7) << 4);
      GLOAD_LDS16(Wcat + (size_t)row * 768 + e * 128 + (colb >> 1), (char*)Blds + off);
    }
    // aggregate type-e in-edges; wave wv owns nodes [wv*16, wv*16+16)
    for (int nl = 0; nl < 16; nl++) {
      int rloc = wv * 16 + nl;
      int n = rbase + rloc;
      float ax = 0.f, ay = 0.f;
      if (n < NN) {
        int idx = n * 6 + e;
        int s = offs6[idx], t = offs6[idx + 1];
        for (int i = s; i < t; i += 4) {   // 4 gathers in flight
          int i1 = i + 1 < t ? i + 1 : t - 1;
          int i2 = i + 2 < t ? i + 2 : t - 1;
          int i3 = i + 3 < t ? i + 3 : t - 1;
          int s0 = entries[i], s1 = entries[i1], s2 = entries[i2], s3 = entries[i3];
          uint_t v0 = *(const uint_t*)(hbf + (size_t)s0 * HD + lane * 2);
          uint_t v1 = *(const uint_t*)(hbf + (size_t)s1 * HD + lane * 2);
          uint_t v2 = *(const uint_t*)(hbf + (size_t)s2 * HD + lane * 2);
          uint_t v3 = *(const uint_t*)(hbf + (size_t)s3 * HD + lane * 2);
          ax += bflo(v0); ay += bfhi(v0);
          if (i + 1 < t) { ax += bflo(v1); ay += bfhi(v1); }
          if (i + 2 < t) { ax += bflo(v2); ay += bfhi(v2); }
          if (i + 3 < t) { ax += bflo(v3); ay += bfhi(v3); }
        }
      }
      int wb = (rloc * 256 + lane * 4) ^ ((rloc & 7) << 4);   // swizzled ds_write
      *(uint_t*)((char*)Alds + wb) = packbf(ax, ay);          // zeros for pad rows
    }
    __syncthreads();
#pragma unroll
    for (int kk = 0; kk < 4; kk++) {
      bf16x8 af[2], bv[4];
#pragma unroll
      for (int m = 0; m < 2; m++) {
        int row = wr * 32 + m * 16 + (lane & 15);
        int b = (row * 256 + kk * 64 + ((lane >> 4) << 4)) ^ ((row & 7) << 4);
        af[m] = *(const bf16x8*)((const char*)Alds + b);
      }
#pragma unroll
      for (int nf = 0; nf < 4; nf++) {
        int row = wc * 64 + nf * 16 + (lane & 15);
        int b = (row * 256 + kk * 64 + ((lane >> 4) << 4)) ^ ((row & 7) << 4);
        bv[nf] = *(const bf16x8*)((const char*)Blds + b);
      }
#pragma unroll
      for (int m = 0; m < 2; m++)
#pragma unroll
        for (int nf = 0; nf < 4; nf++)
          acc[m][nf] = mfma16(af[m], bv[nf], acc[m][nf]);
    }
    __syncthreads();
  }
  // epilogue: msgs = (acc + sum_e cnt_e*b_msg_e)/div + 1e-8
#pragma unroll
  for (int m = 0; m < 2; m++) {
#pragma unroll
    for (int r = 0; r < 4; r++) {
      int node = rbase + wr * 32 + m * 16 + (lane >> 4) * 4 + r;
      if (node < NN) {
        float dv = divf[node];
        const int* c6 = cnt6 + (size_t)node * 6;
#pragma unroll
        for (int nf = 0; nf < 4; nf++) {
          int col = wc * 64 + nf * 16 + (lane & 15);
          float badd = 0.f;
#pragma unroll
          for (int ee = 0; ee < 6; ee++) badd += (float)c6[ee] * b_msg[ee * 128 + col];
          msgs[(size_t)node * HD + col] = f2bf((acc[m][nf][r] + badd) / dv + 1e-8f);
        }
      }
    }
  }
}

// Fused GRU: per block 64 nodes; 8 waves each own 16 output dims with all 6 gate
// columns (ir,iz,in from w_ih x msgs; hr,hz,hn from w_hh x h). Gates in-register.
__global__ __launch_bounds__(512) void k_gru(const ushort_t* __restrict__ msgs,
    const ushort_t* __restrict__ hbf, const ushort_t* __restrict__ wihb,
    const ushort_t* __restrict__ whhb, const float* __restrict__ b_ih,
    const float* __restrict__ b_hh, float* __restrict__ hf,
    ushort_t* __restrict__ hbfo) {
  __shared__ ushort_t Am[64 * 128];
  __shared__ ushort_t Ah[64 * 128];
  int lane = threadIdx.x & 63, wv = threadIdx.x >> 6;
  int rbase = blockIdx.x * 64;
#pragma unroll
  for (int i = 0; i < 2; i++) {
    int off = wv * 1024 + i * 8192;
    int loff = off + lane * 16;
    int r2 = loff >> 8, c16 = (loff >> 4) & 15;
    GLOAD_LDS16(msgs + (size_t)(rbase + r2) * HD + c16 * 8, (char*)Am + off);
    GLOAD_LDS16(hbf  + (size_t)(rbase + r2) * HD + c16 * 8, (char*)Ah + off);
  }
  __syncthreads();
  f32x4 acc[4][6] = {};
#pragma unroll
  for (int ks = 0; ks < 4; ks++) {
    int kb = ks * 64 + ((lane >> 4) << 4);
    bf16x8 am[4], ah[4];
#pragma unroll
    for (int m = 0; m < 4; m++) {
      int rb = (m * 16 + (lane & 15)) * 256 + kb;
      am[m] = *(const bf16x8*)((const char*)Am + rb);
      ah[m] = *(const bf16x8*)((const char*)Ah + rb);
    }
    bf16x8 bi[3], bh[3];
#pragma unroll
    for (int g = 0; g < 3; g++) {
      int n = g * 128 + wv * 16 + (lane & 15);
      int ko = ks * 32 + ((lane >> 4) << 3);
      bi[g] = *(const bf16x8*)(wihb + (size_t)n * HD + ko);
      bh[g] = *(const bf16x8*)(whhb + (size_t)n * HD + ko);
    }
#pragma unroll
    for (int m = 0; m < 4; m++) {
#pragma unroll
      for (int g = 0; g < 3; g++) {
        acc[m][g]     = mfma16(am[m], bi[g], acc[m][g]);
        acc[m][3 + g] = mfma16(ah[m], bh[g], acc[m][3 + g]);
      }
    }
  }
  int d = wv * 16 + (lane & 15);
  float bir = b_ih[d],       bhr = b_hh[d];
  float biz = b_ih[128 + d], bhz = b_hh[128 + d];
  float bin = b_ih[256 + d], bhn = b_hh[256 + d];
#pragma unroll
  for (int m = 0; m < 4; m++) {
#pragma unroll
    for (int r = 0; r < 4; r++) {
      int row = rbase + m * 16 + (lane >> 4) * 4 + r;
      if (row < NN) {
        float ir = acc[m][0][r], iz = acc[m][1][r], in = acc[m][2][r];
        float hr = acc[m][3][r], hz = acc[m][4][r], hn = acc[m][5][r];
        float rg = 1.f / (1.f + expf(-(ir + hr + bir + bhr)));
        float zg = 1.f / (1.f + expf(-(iz + hz + biz + bhz)));
        float ng = tanhf(in + bin + rg * (hn + bhn));
        size_t idx = (size_t)row * HD + d;
        float hold = hf[idx];
        float o = (1.f - zg) * ng + zg * hold;
        hf[idx] = o;
        hbfo[idx] = f2bf(o);
      }
    }
  }
}

// ---------- host ----------

extern "C" void kernel_launch(void* const* d_in, const int* in_sizes, int n_in,
                              void* d_out, int out_size, void* d_ws, size_t ws_size,
                              hipStream_t stream) {
  const float* node_states = (const float*)d_in[0];
  const int*   edges       = (const int*)d_in[1];
  const float* W_msg       = (const float*)d_in[2];
  const float* b_msg       = (const float*)d_in[3];
  const float* w_ih        = (const float*)d_in[4];
  const float* w_hh        = (const float*)d_in[5];
  const float* b_ih        = (const float*)d_in[6];
  const float* b_hh        = (const float*)d_in[7];
  float* out_h   = (float*)d_out;                 // h lives in d_out, updated in place
  float* out_old = out_h + (size_t)NN * HD;

  char* p = (char*)d_ws;
  auto carve = [&](size_t bytes) { char* r = p; p += (bytes + 255) & ~(size_t)255; return r; };
  ushort_t* hbf   = (ushort_t*)carve((size_t)NP * HD * 2);
  ushort_t* msgs  = (ushort_t*)carve((size_t)NP * HD * 2);
  ushort_t* Wcat  = (ushort_t*)carve((size_t)128 * 768 * 2);
  ushort_t* wihb  = (ushort_t*)carve((size_t)384 * 128 * 2);
  ushort_t* whhb  = (ushort_t*)carve((size_t)384 * 128 * 2);
  int*   cnt6     = (int*)carve((size_t)L6 * 4);
  float* divf     = (float*)carve((size_t)NN * 4);
  int*   offs6    = (int*)carve((size_t)(L6 + 1) * 4);
  int*   cursor6  = (int*)carve((size_t)L6 * 4);
  int*   entries  = (int*)carve((size_t)TOT * 4);
  int*   bsum     = (int*)carve(512 * 4);

  hipMemsetAsync(cnt6, 0, (size_t)L6 * 4, stream);
  hipMemsetAsync(hbf  + (size_t)NN * HD, 0, (size_t)(NP - NN) * HD * 2, stream);
  hipMemsetAsync(msgs + (size_t)NN * HD, 0, (size_t)(NP - NN) * HD * 2, stream);

  k_init<<<(NN * HD + 255) / 256, 256, 0, stream>>>(node_states, out_h, out_old, hbf);
  k_prep<<<(128 * 768 + 255) / 256, 256, 0, stream>>>(W_msg, w_ih, w_hh, Wcat, wihb, whhb);
  k_hist<<<(TOT + 255) / 256, 256, 0, stream>>>(edges, cnt6);
  k_div<<<(NN + 255) / 256, 256, 0, stream>>>(cnt6, divf);
  int nb = (L6 + SCHUNK - 1) / SCHUNK;   // 293
  k_scan1<<<nb, 256, 0, stream>>>(cnt6, bsum);
  k_scan2<<<1, 512, 0, stream>>>(bsum, nb);
  k_scan3<<<nb, 256, 0, stream>>>(cnt6, bsum, offs6);
  hipMemcpyAsync(cursor6, offs6, (size_t)L6 * 4, hipMemcpyDeviceToDevice, stream);
  k_fill<<<(TOT + 255) / 256, 256, 0, stream>>>(edges, cursor6, entries);

  for (int L = 0; L < NLAYER; L++) {
    k_msg<<<NP / 128, 512, 0, stream>>>(hbf, offs6, entries, Wcat, cnt6, divf, b_msg, msgs);
    k_gru<<<NP / 64, 512, 0, stream>>>(msgs, hbf, wihb, whhb, b_ih, b_hh, out_h, hbf);
  }
}

// Round 3
// 2271.479 us; speedup vs baseline: 1.6229x; 1.6229x over previous
//
#include <hip/hip_runtime.h>

#define NN     100000
#define NP     100096   // padded to multiple of 128
#define HD     128
#define NE     400000
#define TOT    2400000  // 6 * NE
#define L6     600000   // NN * 6 (per node,type counts)
#define NLAYER 8
#define SCHUNK 2048

typedef unsigned short ushort_t;
typedef unsigned int   uint_t;

typedef __bf16 bf16x8 __attribute__((ext_vector_type(8)));
typedef float  f32x4  __attribute__((ext_vector_type(4)));

__device__ __forceinline__ f32x4 mfma16(bf16x8 a, bf16x8 b, f32x4 c) {
  return __builtin_amdgcn_mfma_f32_16x16x32_bf16(a, b, c, 0, 0, 0);
}

__device__ __forceinline__ unsigned short f2bf(float f) {
  unsigned int u = __builtin_bit_cast(unsigned int, f);
  u = (u + 0x7FFFu + ((u >> 16) & 1u)) >> 16;
  return (unsigned short)u;
}
__device__ __forceinline__ float bflo(uint_t v) { return __builtin_bit_cast(float, v << 16); }
__device__ __forceinline__ float bfhi(uint_t v) { return __builtin_bit_cast(float, v & 0xFFFF0000u); }
__device__ __forceinline__ float bf2f(ushort_t v) { return __builtin_bit_cast(float, (uint_t)v << 16); }
__device__ __forceinline__ uint_t packbf(float x, float y) {
  return (uint_t)f2bf(x) | ((uint_t)f2bf(y) << 16);
}

#define GLOAD_LDS16(g, l) __builtin_amdgcn_global_load_lds( \
    (__attribute__((address_space(1))) void*)(g),           \
    (__attribute__((address_space(3))) void*)(l), 16, 0, 0)

// ---------- setup kernels (once per call) ----------

__global__ __launch_bounds__(256) void k_init(const float* __restrict__ ns,
    float* __restrict__ oh, float* __restrict__ oold, ushort_t* __restrict__ hbf) {
  int i = blockIdx.x * 256 + threadIdx.x;
  if (i < NN * HD) {
    float v = ns[i];
    oh[i] = v; oold[i] = v; hbf[i] = f2bf(v);
  }
}

__global__ __launch_bounds__(256) void k_prep(const float* __restrict__ Wm,
    const float* __restrict__ wih, const float* __restrict__ whh,
    ushort_t* __restrict__ Wcat, ushort_t* __restrict__ wihb, ushort_t* __restrict__ whhb) {
  int t = blockIdx.x * 256 + threadIdx.x;
  if (t < 128 * 768) {
    int n = t / 768, k = t % 768;
    int e = k >> 7, d = k & 127;
    // Wcat[n][k] = W_msg[e][d][n]  (B stored N-major so frags are K-contiguous)
    Wcat[t] = f2bf(Wm[(e * 128 + d) * 128 + n]);
  }
  if (t < 384 * 128) {
    wihb[t] = f2bf(wih[t]);
    whhb[t] = f2bf(whh[t]);
  }
}

__global__ __launch_bounds__(256) void k_hist(const int* __restrict__ edges, int* __restrict__ cnt6) {
  int t = blockIdx.x * 256 + threadIdx.x;
  if (t >= TOT) return;
  int e = t / NE, m = t - e * NE;
  int tgt;
  if (e < 3) tgt = edges[(e * NE + m) * 2 + 1];
  else       tgt = edges[((e - 3) * NE + m) * 2];
  atomicAdd(&cnt6[tgt * 6 + e], 1);
}

__global__ __launch_bounds__(256) void k_div(const int* __restrict__ cnt6,
    float* __restrict__ divf) {
  int i = blockIdx.x * 256 + threadIdx.x;
  if (i < NN) {
    int c = 0;
#pragma unroll
    for (int e = 0; e < 6; e++) c += cnt6[i * 6 + e];
    divf[i] = c ? (float)c : 1.0f;
  }
}

// exclusive scan over cnt6 (length L6) -> offs6 (length L6+1)
__global__ __launch_bounds__(256) void k_scan1(const int* __restrict__ cnt, int* __restrict__ bsum) {
  int base = blockIdx.x * SCHUNK + threadIdx.x * 8;
  int s = 0;
#pragma unroll
  for (int j = 0; j < 8; j++) { int idx = base + j; s += (idx < L6) ? cnt[idx] : 0; }
  for (int o = 32; o > 0; o >>= 1) s += __shfl_down(s, o);
  __shared__ int sm[4];
  if ((threadIdx.x & 63) == 0) sm[threadIdx.x >> 6] = s;
  __syncthreads();
  if (threadIdx.x == 0) bsum[blockIdx.x] = sm[0] + sm[1] + sm[2] + sm[3];
}

__global__ __launch_bounds__(512) void k_scan2(int* __restrict__ bsum, int nb) { // 1 block, nb<=512
  int t = threadIdx.x, lane = t & 63, wv = t >> 6;
  int orig = (t < nb) ? bsum[t] : 0;
  int v = orig;
  for (int o = 1; o < 64; o <<= 1) { int x = __shfl_up(v, o); if (lane >= o) v += x; }
  __shared__ int ws[8];
  if (lane == 63) ws[wv] = v;
  __syncthreads();
  int add = 0;
  for (int w = 0; w < wv; w++) add += ws[w];
  if (t < nb) bsum[t] = v - orig + add;   // exclusive
}

__global__ __launch_bounds__(256) void k_scan3(const int* __restrict__ cnt,
    const int* __restrict__ bsum, int* __restrict__ offs) {
  int base = blockIdx.x * SCHUNK + threadIdx.x * 8;
  int vals[8], pre[8];
  int s = 0;
#pragma unroll
  for (int j = 0; j < 8; j++) {
    int idx = base + j;
    vals[j] = (idx < L6) ? cnt[idx] : 0;
    pre[j] = s; s += vals[j];
  }
  int lane = threadIdx.x & 63, wvi = threadIdx.x >> 6;
  int v = s;
  for (int o = 1; o < 64; o <<= 1) { int t = __shfl_up(v, o); if (lane >= o) v += t; }
  __shared__ int wsum[4];
  if (lane == 63) wsum[wvi] = v;
  __syncthreads();
  int wpre = 0;
  for (int w = 0; w < wvi; w++) wpre += wsum[w];
  int texcl = (v - s) + wpre + bsum[blockIdx.x];
#pragma unroll
  for (int j = 0; j < 8; j++) {
    int idx = base + j;
    if (idx < L6) {
      offs[idx] = texcl + pre[j];
      if (idx == L6 - 1) offs[L6] = texcl + pre[j] + vals[j];
    }
  }
}

__global__ __launch_bounds__(256) void k_fill(const int* __restrict__ edges,
    int* __restrict__ cursor6, int* __restrict__ entries) {
  int t = blockIdx.x * 256 + threadIdx.x;
  if (t >= TOT) return;
  int e = t / NE, m = t - e * NE;
  int src, tgt;
  if (e < 3) { int b = (e * NE + m) * 2;       src = edges[b];     tgt = edges[b + 1]; }
  else       { int b = ((e - 3) * NE + m) * 2; src = edges[b + 1]; tgt = edges[b]; }
  int pos = atomicAdd(&cursor6[tgt * 6 + e], 1);
  entries[pos] = src;   // type implied by segment
}

// ---------- per-layer kernels ----------

// Wave-per-node CSR aggregation over the type-sorted edge list.
// Scalarized edge stream: one coalesced 64-entry preload, readlane per edge ->
// SALU addresses; running (cx,cy) accumulator flushed into per-type registers
// only at the <=6 uniform segment boundaries.
#define FLUSH() do { switch (curE) {                        \
    case 0: a0x += cx; a0y += cy; break;                    \
    case 1: a1x += cx; a1y += cy; break;                    \
    case 2: a2x += cx; a2y += cy; break;                    \
    case 3: a3x += cx; a3y += cy; break;                    \
    case 4: a4x += cx; a4y += cy; break;                    \
    default: a5x += cx; a5y += cy; break; }                 \
    cx = 0.f; cy = 0.f; } while (0)

#define ADV() do { while (curE < 5 && pos == nextB) {       \
    FLUSH(); curE++;                                        \
    nextB = __builtin_amdgcn_readlane(bj, curE + 1); } } while (0)

__global__ __launch_bounds__(512) void k_agg(const ushort_t* __restrict__ hbf,
    const int* __restrict__ offs6, const int* __restrict__ entries,
    ushort_t* __restrict__ agg, int node0, int rows) {
  int lane = threadIdx.x & 63, wv = threadIdx.x >> 6;
  int row = blockIdx.x * 8 + wv;
  if (row >= rows) return;
  int n = node0 + row;
  float a0x = 0.f, a0y = 0.f, a1x = 0.f, a1y = 0.f, a2x = 0.f, a2y = 0.f;
  float a3x = 0.f, a3y = 0.f, a4x = 0.f, a4y = 0.f, a5x = 0.f, a5y = 0.f;
  if (n < NN) {
    int bj = offs6[n * 6 + (lane < 6 ? lane : 6)];   // lane j holds S[min(j,6)]
    int S0 = __builtin_amdgcn_readlane(bj, 0);
    int S6 = __builtin_amdgcn_readlane(bj, 6);
    int deg = S6 - S0;
    int curE = 0;
    int nextB = __builtin_amdgcn_readlane(bj, 1);
    float cx = 0.f, cy = 0.f;
    int pos = S0;
    int voff = lane * 4;
    const char* hb = (const char*)hbf;
    for (int c0 = 0; c0 < deg; c0 += 64) {
      int m = deg - c0; if (m > 64) m = 64;
      int ent = entries[S0 + c0 + (lane < m ? lane : 0)];
      for (int j = 0; j < m; j += 4) {
        int j1 = j + 1 < m ? j + 1 : m - 1;
        int j2 = j + 2 < m ? j + 2 : m - 1;
        int j3 = j + 3 < m ? j + 3 : m - 1;
        int s0_ = __builtin_amdgcn_readlane(ent, j);
        int s1_ = __builtin_amdgcn_readlane(ent, j1);
        int s2_ = __builtin_amdgcn_readlane(ent, j2);
        int s3_ = __builtin_amdgcn_readlane(ent, j3);
        uint_t v0 = *(const uint_t*)(hb + ((size_t)(uint_t)s0_ << 8) + voff);
        uint_t v1 = *(const uint_t*)(hb + ((size_t)(uint_t)s1_ << 8) + voff);
        uint_t v2 = *(const uint_t*)(hb + ((size_t)(uint_t)s2_ << 8) + voff);
        uint_t v3 = *(const uint_t*)(hb + ((size_t)(uint_t)s3_ << 8) + voff);
        ADV(); cx += bflo(v0); cy += bfhi(v0); pos++;
        if (j + 1 < m) { ADV(); cx += bflo(v1); cy += bfhi(v1); pos++; }
        if (j + 2 < m) { ADV(); cx += bflo(v2); cy += bfhi(v2); pos++; }
        if (j + 3 < m) { ADV(); cx += bflo(v3); cy += bfhi(v3); pos++; }
      }
    }
    ADV();     // flush through any trailing empty segments
    FLUSH();   // final segment
  }
  uint_t* outp = (uint_t*)(agg + (size_t)row * 768);
  outp[0 * 64 + lane] = packbf(a0x, a0y);
  outp[1 * 64 + lane] = packbf(a1x, a1y);
  outp[2 * 64 + lane] = packbf(a2x, a2y);
  outp[3 * 64 + lane] = packbf(a3x, a3y);
  outp[4 * 64 + lane] = packbf(a4x, a4y);
  outp[5 * 64 + lane] = packbf(a5x, a5y);
}

// msgs = (agg_cat @ Wcat + sum_e cnt_e*b_msg_e) / div + 1e-8 ; M-tile 128, N=128, K=768
__global__ __launch_bounds__(256) void k_gemm1(const ushort_t* __restrict__ agg,
    const ushort_t* __restrict__ Wcat, const int* __restrict__ cnt6,
    const float* __restrict__ divf, const float* __restrict__ b_msg,
    ushort_t* __restrict__ msgs, int node0) {
  __shared__ ushort_t Alds[128 * 64];
  __shared__ ushort_t Blds[128 * 64];
  int lane = threadIdx.x & 63, wv = threadIdx.x >> 6;
  int wr = wv >> 1, wc = wv & 1;
  int rbase = blockIdx.x * 128;
  f32x4 acc[4][4] = {};
  for (int k0 = 0; k0 < 768; k0 += 64) {
#pragma unroll
    for (int i = 0; i < 4; i++) {
      int off = wv * 1024 + i * 4096;         // wave-uniform LDS base
      int loff = off + lane * 16;             // this lane's slot
      int r2 = loff >> 7, c16 = (loff >> 4) & 7;
      GLOAD_LDS16(agg + (size_t)(rbase + r2) * 768 + k0 + c16 * 8, (char*)Alds + off);
      GLOAD_LDS16(Wcat + (size_t)r2 * 768 + k0 + c16 * 8,          (char*)Blds + off);
    }
    __syncthreads();
#pragma unroll
    for (int kk = 0; kk < 2; kk++) {
      int kb = kk * 64 + ((lane >> 4) << 4);
      bf16x8 af[4], bfv[4];
#pragma unroll
      for (int m = 0; m < 4; m++) {
        af[m]  = *(const bf16x8*)((const char*)Alds + (wr * 64 + m * 16 + (lane & 15)) * 128 + kb);
        bfv[m] = *(const bf16x8*)((const char*)Blds + (wc * 64 + m * 16 + (lane & 15)) * 128 + kb);
      }
#pragma unroll
      for (int m = 0; m < 4; m++)
#pragma unroll
        for (int nf = 0; nf < 4; nf++)
          acc[m][nf] = mfma16(af[m], bfv[nf], acc[m][nf]);
    }
    __syncthreads();
  }
#pragma unroll
  for (int m = 0; m < 4; m++) {
#pragma unroll
    for (int r = 0; r < 4; r++) {
      int node = node0 + rbase + wr * 64 + m * 16 + (lane >> 4) * 4 + r;
      if (node < NN) {
        float dv = divf[node];
        const int* c6 = cnt6 + (size_t)node * 6;
#pragma unroll
        for (int nf = 0; nf < 4; nf++) {
          int col = wc * 64 + nf * 16 + (lane & 15);
          float badd = 0.f;
#pragma unroll
          for (int e = 0; e < 6; e++) badd += (float)c6[e] * b_msg[e * 128 + col];
          float v = (acc[m][nf][r] + badd) / dv + 1e-8f;
          msgs[(size_t)node * HD + col] = f2bf(v);
        }
      }
    }
  }
}

// Fused GRU: per block 64 nodes; 8 waves each own 16 output dims with all 6 gate
// columns. h kept in bf16 only (h_old read from the staged LDS tile); f32 d_out
// written on the last layer only.
__global__ __launch_bounds__(512) void k_gru(const ushort_t* __restrict__ msgs,
    const ushort_t* __restrict__ hbf, const ushort_t* __restrict__ wihb,
    const ushort_t* __restrict__ whhb, const float* __restrict__ b_ih,
    const float* __restrict__ b_hh, float* __restrict__ hf,
    ushort_t* __restrict__ hbfo, int last) {
  __shared__ ushort_t Am[64 * 128];
  __shared__ ushort_t Ah[64 * 128];
  int lane = threadIdx.x & 63, wv = threadIdx.x >> 6;
  int rbase = blockIdx.x * 64;
#pragma unroll
  for (int i = 0; i < 2; i++) {
    int off = wv * 1024 + i * 8192;
    int loff = off + lane * 16;
    int r2 = loff >> 8, c16 = (loff >> 4) & 15;
    GLOAD_LDS16(msgs + (size_t)(rbase + r2) * HD + c16 * 8, (char*)Am + off);
    GLOAD_LDS16(hbf  + (size_t)(rbase + r2) * HD + c16 * 8, (char*)Ah + off);
  }
  __syncthreads();
  f32x4 acc[4][6] = {};
#pragma unroll
  for (int ks = 0; ks < 4; ks++) {
    int kb = ks * 64 + ((lane >> 4) << 4);
    bf16x8 am[4], ah[4];
#pragma unroll
    for (int m = 0; m < 4; m++) {
      int rb = (m * 16 + (lane & 15)) * 256 + kb;
      am[m] = *(const bf16x8*)((const char*)Am + rb);
      ah[m] = *(const bf16x8*)((const char*)Ah + rb);
    }
    bf16x8 bi[3], bh[3];
#pragma unroll
    for (int g = 0; g < 3; g++) {
      int n = g * 128 + wv * 16 + (lane & 15);
      int ko = ks * 32 + ((lane >> 4) << 3);
      bi[g] = *(const bf16x8*)(wihb + (size_t)n * HD + ko);
      bh[g] = *(const bf16x8*)(whhb + (size_t)n * HD + ko);
    }
#pragma unroll
    for (int m = 0; m < 4; m++) {
#pragma unroll
      for (int g = 0; g < 3; g++) {
        acc[m][g]     = mfma16(am[m], bi[g], acc[m][g]);
        acc[m][3 + g] = mfma16(ah[m], bh[g], acc[m][3 + g]);
      }
    }
  }
  int d = wv * 16 + (lane & 15);
  float bir = b_ih[d],       bhr = b_hh[d];
  float biz = b_ih[128 + d], bhz = b_hh[128 + d];
  float bin = b_ih[256 + d], bhn = b_hh[256 + d];
#pragma unroll
  for (int m = 0; m < 4; m++) {
#pragma unroll
    for (int r = 0; r < 4; r++) {
      int rloc = m * 16 + (lane >> 4) * 4 + r;
      int row = rbase + rloc;
      if (row < NN) {
        float ir = acc[m][0][r], iz = acc[m][1][r], in = acc[m][2][r];
        float hr = acc[m][3][r], hz = acc[m][4][r], hn = acc[m][5][r];
        float rg = 1.f / (1.f + expf(-(ir + hr + bir + bhr)));
        float zg = 1.f / (1.f + expf(-(iz + hz + biz + bhz)));
        float ng = tanhf(in + bin + rg * (hn + bhn));
        float hold = bf2f(Ah[rloc * 128 + d]);
        float o = (1.f - zg) * ng + zg * hold;
        size_t idx = (size_t)row * HD + d;
        hbfo[idx] = f2bf(o);
        if (last) hf[idx] = o;
      }
    }
  }
}

// ---------- host ----------

extern "C" void kernel_launch(void* const* d_in, const int* in_sizes, int n_in,
                              void* d_out, int out_size, void* d_ws, size_t ws_size,
                              hipStream_t stream) {
  const float* node_states = (const float*)d_in[0];
  const int*   edges       = (const int*)d_in[1];
  const float* W_msg       = (const float*)d_in[2];
  const float* b_msg       = (const float*)d_in[3];
  const float* w_ih        = (const float*)d_in[4];
  const float* w_hh        = (const float*)d_in[5];
  const float* b_ih        = (const float*)d_in[6];
  const float* b_hh        = (const float*)d_in[7];
  float* out_h   = (float*)d_out;
  float* out_old = out_h + (size_t)NN * HD;

  char* p = (char*)d_ws;
  auto carve = [&](size_t bytes) { char* r = p; p += (bytes + 255) & ~(size_t)255; return r; };
  ushort_t* hbf   = (ushort_t*)carve((size_t)NP * HD * 2);
  ushort_t* msgs  = (ushort_t*)carve((size_t)NP * HD * 2);
  ushort_t* Wcat  = (ushort_t*)carve((size_t)128 * 768 * 2);
  ushort_t* wihb  = (ushort_t*)carve((size_t)384 * 128 * 2);
  ushort_t* whhb  = (ushort_t*)carve((size_t)384 * 128 * 2);
  int*   cnt6     = (int*)carve((size_t)L6 * 4);
  float* divf     = (float*)carve((size_t)NN * 4);
  int*   offs6    = (int*)carve((size_t)(L6 + 1) * 4);
  int*   cursor6  = (int*)carve((size_t)L6 * 4);
  int*   entries  = (int*)carve((size_t)TOT * 4);
  int*   bsum     = (int*)carve(512 * 4);
  size_t used  = (size_t)(p - (char*)d_ws);
  size_t avail = ws_size > used ? ws_size - used : 0;
  size_t chunk_rows = avail / (768 * 2);
  if (chunk_rows > (size_t)NP) chunk_rows = NP;
  chunk_rows &= ~(size_t)127;
  if (chunk_rows < 128) chunk_rows = 128;
  ushort_t* agg = (ushort_t*)p;

  hipMemsetAsync(cnt6, 0, (size_t)L6 * 4, stream);
  hipMemsetAsync(hbf  + (size_t)NN * HD, 0, (size_t)(NP - NN) * HD * 2, stream);
  hipMemsetAsync(msgs + (size_t)NN * HD, 0, (size_t)(NP - NN) * HD * 2, stream);

  k_init<<<(NN * HD + 255) / 256, 256, 0, stream>>>(node_states, out_h, out_old, hbf);
  k_prep<<<(128 * 768 + 255) / 256, 256, 0, stream>>>(W_msg, w_ih, w_hh, Wcat, wihb, whhb);
  k_hist<<<(TOT + 255) / 256, 256, 0, stream>>>(edges, cnt6);
  k_div<<<(NN + 255) / 256, 256, 0, stream>>>(cnt6, divf);
  int nb = (L6 + SCHUNK - 1) / SCHUNK;   // 293
  k_scan1<<<nb, 256, 0, stream>>>(cnt6, bsum);
  k_scan2<<<1, 512, 0, stream>>>(bsum, nb);
  k_scan3<<<nb, 256, 0, stream>>>(cnt6, bsum, offs6);
  hipMemcpyAsync(cursor6, offs6, (size_t)L6 * 4, hipMemcpyDeviceToDevice, stream);
  k_fill<<<(TOT + 255) / 256, 256, 0, stream>>>(edges, cursor6, entries);

  for (int L = 0; L < NLAYER; L++) {
    for (size_t n0 = 0; n0 < (size_t)NP; n0 += chunk_rows) {
      int rows = (int)(((size_t)NP - n0) < chunk_rows ? ((size_t)NP - n0) : chunk_rows);
      k_agg<<<(rows + 7) / 8, 512, 0, stream>>>(hbf, offs6, entries, agg, (int)n0, rows);
      k_gemm1<<<rows / 128, 256, 0, stream>>>(agg, Wcat, cnt6, divf, b_msg, msgs, (int)n0);
    }
    k_gru<<<NP / 64, 512, 0, stream>>>(msgs, hbf, wihb, whhb, b_ih, b_hh,
                                       out_h, hbf, L == NLAYER - 1);
  }
}